// Round 1
// baseline (359.175 us; speedup 1.0000x reference)
//
#include <hip/hip_runtime.h>

typedef float f32x2 __attribute__((ext_vector_type(2)));
typedef float f32x4 __attribute__((ext_vector_type(4)));

#define LOG2E 1.44269504088896340736f

__device__ __forceinline__ float rcp_fast(float x) { return __builtin_amdgcn_rcpf(x); }

__device__ __forceinline__ f32x2 mk2(float a, float b) { f32x2 v; v[0] = a; v[1] = b; return v; }

__device__ __forceinline__ float sigmoid_fast(float x) {
    // 1/(1+exp(-x)); exp2 overflow -> inf -> rcp -> 0 (correct limit), no NaN
    return rcp_fast(1.0f + __builtin_amdgcn_exp2f(-LOG2E * x));
}

__device__ __forceinline__ float tanh_fast(float x) {
    // overflow-safe: t = exp2(-2*log2e*|x|) in (0,1]
    float a = __builtin_fabsf(x);
    float t = __builtin_amdgcn_exp2f(-2.0f * LOG2E * a);
    float r = (1.0f - t) * rcp_fast(1.0f + t);
    return __builtin_copysignf(r, x);
}

// Read 16 contiguous floats from LDS as 4x ds_read_b128, emit 8 float2 pairs.
__device__ __forceinline__ void load_pairs16(const float* p, f32x2* dst) {
    const f32x4* q4 = (const f32x4*)p;
    f32x4 a = q4[0], b = q4[1], c = q4[2], d = q4[3];
    dst[0] = __builtin_shufflevector(a, a, 0, 1);
    dst[1] = __builtin_shufflevector(a, a, 2, 3);
    dst[2] = __builtin_shufflevector(b, b, 0, 1);
    dst[3] = __builtin_shufflevector(b, b, 2, 3);
    dst[4] = __builtin_shufflevector(c, c, 0, 1);
    dst[5] = __builtin_shufflevector(c, c, 2, 3);
    dst[6] = __builtin_shufflevector(d, d, 0, 1);
    dst[7] = __builtin_shufflevector(d, d, 2, 3);
}

// One wave (64 threads) = 4 batch elements; lane j in [0,16) = hidden index.
// Lane j holds register-resident: W_in row j (gamma-folded), W_ih/W_hh rows
// {j, j+16, j+32, j+48} as k-packed float2 (v_pk_fma_f32), W_out row j (j<12).
__global__ __launch_bounds__(64) void vm_kernel(
    const float* __restrict__ init_state,  // (B,1,12)
    const float* __restrict__ commands,    // (B,T,4)
    const float* __restrict__ ln_g,        // (16)
    const float* __restrict__ ln_b,        // (16)
    const float* __restrict__ W_in,        // (16,16)
    const float* __restrict__ b_in,        // (16)
    const float* __restrict__ W_ih,        // (64,16)
    const float* __restrict__ W_hh,        // (64,16)
    const float* __restrict__ b_ih,        // (64)
    const float* __restrict__ b_hh,        // (64)
    const float* __restrict__ W_out,       // (12,16)
    const float* __restrict__ b_out,       // (12)
    float* __restrict__ out,               // (B,T,12)
    int B, int T)
{
    const int lane = threadIdx.x;
    const int j = lane & 15;
    const int g = lane >> 4;
    const int b = blockIdx.x * 4 + g;

    // Row strides padded (20, 36) so the group-broadcast ds_read_b128s hit
    // disjoint bank quads across the 4 groups (conflict-free).
    __shared__ float sh_x[4][20];    // x = concat(state, cmd)
    __shared__ float sh_xhh[4][36];  // [0..15]=xh, [16..31]=h
    __shared__ float sh_hn[4][20];   // new h

    // ---- preamble: weights into registers (one-time, L2-cached) ----
    f32x2 Wg2[8];       // W_in row j with ln_gamma folded in
    float wbeta;        // b_in[j] + W_in[j,:].ln_beta
    float sWg = 0.0f;   // sum_k Wg[j][k]
    {
        const float* wr = W_in + j * 16;
        float bsum = b_in[j];
        float ssum = 0.0f;
#pragma unroll
        for (int k2 = 0; k2 < 8; ++k2) {
            float w0 = wr[2 * k2], w1 = wr[2 * k2 + 1];
            float g0 = ln_g[2 * k2], g1 = ln_g[2 * k2 + 1];
            float a0 = w0 * g0, a1 = w1 * g1;
            Wg2[k2] = mk2(a0, a1);
            bsum += w0 * ln_b[2 * k2] + w1 * ln_b[2 * k2 + 1];
            ssum += a0 + a1;
        }
        wbeta = bsum;
        sWg = ssum;
    }

    f32x2 Wx[4][8], Wh[4][8];  // gate rows (i,f,g,o) for hidden j, k-packed
    float gb[4];
#pragma unroll
    for (int q = 0; q < 4; ++q) {
        const float* rx = W_ih + (q * 16 + j) * 16;
        const float* rh = W_hh + (q * 16 + j) * 16;
#pragma unroll
        for (int k2 = 0; k2 < 8; ++k2) {
            Wx[q][k2] = mk2(rx[2 * k2], rx[2 * k2 + 1]);
            Wh[q][k2] = mk2(rh[2 * k2], rh[2 * k2 + 1]);
        }
        gb[q] = b_ih[q * 16 + j] + b_hh[q * 16 + j];
    }

    f32x2 Wo[8];
    float bo = 0.0f;
#pragma unroll
    for (int k2 = 0; k2 < 8; ++k2) Wo[k2] = mk2(0.0f, 0.0f);
    if (j < 12) {
        const float* ro = W_out + j * 16;
#pragma unroll
        for (int k2 = 0; k2 < 8; ++k2) Wo[k2] = mk2(ro[2 * k2], ro[2 * k2 + 1]);
        bo = b_out[j];
    }

    // ---- per-batch recurrent state ----
    const bool is_state = (j < 12);
    float st = is_state ? init_state[b * 12 + j] : 0.0f;
    float h = 0.0f, c = 0.0f;

    const float* cmd_ptr = commands + (size_t)b * T * 4 + (j - 12);
    float cmd = (j >= 12) ? cmd_ptr[0] : 0.0f;

    float* out_ptr = out + (size_t)b * T * 12 + j;

    // sincos partner lane: pairs (1,2),(3,4),(5,6)
    int pj = j;
    if (j >= 1 && j <= 6) pj = ((j - 1) ^ 1) + 1;
    const int psrc = (lane & 48) | pj;
    const bool donorm = (j >= 1 && j <= 6);

    for (int t = 0; t < T; ++t) {
        // stage x = concat(state, cmd)
        float x = is_state ? st : cmd;
        sh_x[g][j] = x;

        // software-prefetch next step's command
        float cmd_next = 0.0f;
        {
            int tn = (t + 1 < T) ? (t + 1) : t;
            if (j >= 12) cmd_next = cmd_ptr[(size_t)tn * 4];
        }
        __syncthreads();

        f32x2 xp[8];
        load_pairs16(&sh_x[g][0], xp);

        // LN stats (one-pass) + folded W_in dot, all from the same regs
        f32x2 s2 = ((xp[0] + xp[1]) + (xp[2] + xp[3])) + ((xp[4] + xp[5]) + (xp[6] + xp[7]));
        float sum = s2[0] + s2[1];
        f32x2 q2 = xp[0] * xp[0];
#pragma unroll
        for (int k2 = 1; k2 < 8; ++k2) q2 += xp[k2] * xp[k2];
        float sumsq = q2[0] + q2[1];
        float mu = sum * 0.0625f;
        float var = sumsq * 0.0625f - mu * mu;
        float inv = __builtin_amdgcn_rsqf(var + 1e-5f);

        f32x2 d2 = Wg2[0] * xp[0];
#pragma unroll
        for (int k2 = 1; k2 < 8; ++k2) d2 += Wg2[k2] * xp[k2];
        float xh = ((d2[0] + d2[1]) - mu * sWg) * inv + wbeta;

        sh_xhh[g][j] = xh;
        sh_xhh[g][16 + j] = h;
        __syncthreads();

        f32x2 ap[8], hp[8];
        load_pairs16(&sh_xhh[g][0], ap);
        load_pairs16(&sh_xhh[g][16], hp);

        f32x2 ai = mk2(0.f, 0.f), af = mk2(0.f, 0.f), ag = mk2(0.f, 0.f), ao = mk2(0.f, 0.f);
#pragma unroll
        for (int k2 = 0; k2 < 8; ++k2) {
            f32x2 xv = ap[k2], hv = hp[k2];
            ai += Wx[0][k2] * xv; af += Wx[1][k2] * xv;
            ag += Wx[2][k2] * xv; ao += Wx[3][k2] * xv;
            ai += Wh[0][k2] * hv; af += Wh[1][k2] * hv;
            ag += Wh[2][k2] * hv; ao += Wh[3][k2] * hv;
        }
        float gi = ai[0] + ai[1] + gb[0];
        float gf = af[0] + af[1] + gb[1];
        float gg = ag[0] + ag[1] + gb[2];
        float go = ao[0] + ao[1] + gb[3];

        float iv = sigmoid_fast(gi);
        float fv = sigmoid_fast(gf);
        float gv = tanh_fast(gg);
        float ov = sigmoid_fast(go);
        c = fv * c + iv * gv;
        h = ov * tanh_fast(c);

        sh_hn[g][j] = h;
        __syncthreads();

        f32x2 hn[8];
        load_pairs16(&sh_hn[g][0], hn);
        f32x2 o2 = Wo[0] * hn[0];
#pragma unroll
        for (int k2 = 1; k2 < 8; ++k2) o2 += Wo[k2] * hn[k2];

        if (is_state) st += (o2[0] + o2[1]) + bo;

        // sincos pair renorm (uses pre-update copies of both — parallel update matches ref)
        float pv = __shfl(st, psrc, 64);
        if (donorm) {
            float n = __builtin_amdgcn_sqrtf(st * st + pv * pv) + 1e-8f;
            st *= rcp_fast(n);
        }

        if (is_state) out_ptr[0] = st;
        out_ptr += 12;
        cmd = cmd_next;
    }
}

extern "C" void kernel_launch(void* const* d_in, const int* in_sizes, int n_in,
                              void* d_out, int out_size, void* d_ws, size_t ws_size,
                              hipStream_t stream) {
    const float* init_state = (const float*)d_in[0];
    const float* commands   = (const float*)d_in[1];
    const float* ln_g       = (const float*)d_in[2];
    const float* ln_b       = (const float*)d_in[3];
    const float* W_in       = (const float*)d_in[4];
    const float* b_in       = (const float*)d_in[5];
    const float* W_ih       = (const float*)d_in[6];
    const float* W_hh       = (const float*)d_in[7];
    const float* b_ih       = (const float*)d_in[8];
    const float* b_hh       = (const float*)d_in[9];
    const float* W_out      = (const float*)d_in[10];
    const float* b_out      = (const float*)d_in[11];

    int B = in_sizes[0] / 12;           // 8192
    int T = in_sizes[1] / (B * 4);      // 256

    int blocks = B / 4;                 // 4 batch elements per 64-thread block
    vm_kernel<<<blocks, 64, 0, stream>>>(init_state, commands, ln_g, ln_b,
                                         W_in, b_in, W_ih, W_hh, b_ih, b_hh,
                                         W_out, b_out, (float*)d_out, B, T);
}